// Round 2
// baseline (1908.022 us; speedup 1.0000x reference)
//
#include <hip/hip_runtime.h>

// ---------------- types / helpers ----------------
typedef __attribute__((ext_vector_type(8))) short short8;
typedef __attribute__((ext_vector_type(4))) float f32x4;
typedef unsigned short u16;

#define N_TOK   1536
#define DMODEL  1024
#define NHEAD   16
#define DHEAD   64
#define NCTX    512
#define INNERD  2730
#define INNERP  2752   // K-padded inner
#define FF1P    5504   // N-padded 2*inner
#define VOCAB   8192

__device__ __forceinline__ u16 f2b(float f) {
  union { float f; unsigned u; } v; v.f = f;
  unsigned r = (v.u >> 16) & 1u;
  return (u16)((v.u + 0x7fffu + r) >> 16);
}

// ---------------- weight convert+transpose: f32 [z][K][Nw] -> bf16 [z][..][Kpad], out[n][k]=in[k][n]
// 64x64 tile, float4 global loads, short8 global stores.
__global__ __launch_bounds__(256) void conv_t(
    const float* __restrict__ in, u16* __restrict__ out,
    int K, int Nw, int Kpad, int Nbound, long long zin, long long zout)
{
  const float* inl = in + (size_t)blockIdx.z * zin;
  u16* outl = out + (size_t)blockIdx.z * zout;
  __shared__ float tile[64][65];
  int k0 = blockIdx.x * 64, n0 = blockIdx.y * 64;
  int tid = threadIdx.x;
  {
    int r = tid >> 4, c4 = (tid & 15) * 4;
#pragma unroll
    for (int j = 0; j < 4; j++) {
      int k = k0 + r + j * 16;
      float4 v = make_float4(0.f, 0.f, 0.f, 0.f);
      if (k < K && (n0 + c4) < Nw) v = *(const float4*)&inl[(size_t)k * Nw + n0 + c4];
      tile[r + j * 16][c4] = v.x; tile[r + j * 16][c4 + 1] = v.y;
      tile[r + j * 16][c4 + 2] = v.z; tile[r + j * 16][c4 + 3] = v.w;
    }
  }
  __syncthreads();
  {
    int nl = tid >> 2, kc = (tid & 3) * 16;
    int n = n0 + nl;
    if (n < Nbound) {
      u16 pk[16];
#pragma unroll
      for (int i = 0; i < 16; i++) pk[i] = f2b(tile[kc + i][nl]);
      u16* op = outl + (size_t)n * Kpad + k0 + kc;
      *(short8*)&op[0] = *(short8*)&pk[0];
      *(short8*)&op[8] = *(short8*)&pk[8];
    }
  }
}

// ---------------- embeddings ----------------
__global__ void embed_img(const int* __restrict__ x, const float* __restrict__ temb,
                          const float* __restrict__ pemb, float* __restrict__ h) {
  int n = blockIdx.x; int tok = x[n]; int d4 = threadIdx.x;
  float4 a = *(const float4*)&temb[(size_t)tok * DMODEL + d4 * 4];
  float4 b = *(const float4*)&pemb[(size_t)n * DMODEL + d4 * 4];
  float4 o; o.x = a.x + b.x; o.y = a.y + b.y; o.z = a.z + b.z; o.w = a.w + b.w;
  *(float4*)&h[(size_t)n * DMODEL + d4 * 4] = o;
}

__global__ void embed_ctx(const int* __restrict__ ids, const float* __restrict__ temb,
                          const float* __restrict__ pemb, u16* __restrict__ ctxb) {
  int n = blockIdx.x; int tok = ids[n]; int d4 = threadIdx.x;
  float4 a = *(const float4*)&temb[(size_t)tok * DMODEL + d4 * 4];
  float4 b = *(const float4*)&pemb[(size_t)n * DMODEL + d4 * 4];
  u16* o = ctxb + (size_t)n * DMODEL + d4 * 4;
  o[0] = f2b(a.x + b.x); o[1] = f2b(a.y + b.y); o[2] = f2b(a.z + b.z); o[3] = f2b(a.w + b.w);
}

// ---------------- LayerNorm -> bf16 ----------------
__global__ __launch_bounds__(256) void ln_bf16(
    const float* __restrict__ X, int ldin, const float* __restrict__ g,
    u16* __restrict__ Y, int ldout, int C, int Cpad)
{
  int row = blockIdx.x;
  const float* x = X + (size_t)row * ldin;
  float s = 0.f, sq = 0.f;
  for (int ci = threadIdx.x; ci < C; ci += 256) { float v = x[ci]; s += v; sq += v * v; }
#pragma unroll
  for (int m = 1; m < 64; m <<= 1) { s += __shfl_xor(s, m, 64); sq += __shfl_xor(sq, m, 64); }
  __shared__ float red[2][4];
  int w = threadIdx.x >> 6;
  if ((threadIdx.x & 63) == 0) { red[0][w] = s; red[1][w] = sq; }
  __syncthreads();
  s = red[0][0] + red[0][1] + red[0][2] + red[0][3];
  sq = red[1][0] + red[1][1] + red[1][2] + red[1][3];
  float mean = s / C;
  float var = sq / C - mean * mean;
  float rstd = rsqrtf(var + 1e-5f);
  u16* y = Y + (size_t)row * ldout;
  for (int ci = threadIdx.x; ci < C; ci += 256) y[ci] = f2b((x[ci] - mean) * rstd * g[ci]);
  for (int ci = C + threadIdx.x; ci < Cpad; ci += 256) y[ci] = 0;
}

// ---------------- GEMM: C(M,N) = A(M,K)bf16 @ Bt(N,K)bf16, 128x128 tile, BK=64 ----------------
// WMODE: 0 = store, 1 = read-modify-write (+=, single writer), 2 = atomicAdd (split-K)
template <int WMODE, int NSPLIT>
__global__ __launch_bounds__(256) void gemm_bt(
    const u16* __restrict__ A, const u16* __restrict__ Bt,
    float* __restrict__ C, int ldc, int M, int N, int K, int lda, int ldb)
{
  __shared__ __align__(16) short As[128 * 72];
  __shared__ __align__(16) short Bs[128 * 72];
  int tid = threadIdx.x;
  int bm = blockIdx.x, bn = blockIdx.y;
  int lane = tid & 63, w = tid >> 6;
  int wm = (w >> 1) * 64, wn = (w & 1) * 64;
  int rl = lane & 15, quad = lane >> 4;
  f32x4 acc[4][4];
#pragma unroll
  for (int i = 0; i < 4; i++)
#pragma unroll
    for (int j = 0; j < 4; j++) acc[i][j] = (f32x4)(0.f);
  const int rowA0 = bm * 128, rowB0 = bn * 128;
  int tiles = K >> 6;
  int t0 = (tiles * blockIdx.z) / NSPLIT, t1 = (tiles * (blockIdx.z + 1)) / NSPLIT;

  for (int kt = t0; kt < t1; kt++) {
    int k0 = kt * 64;
    __syncthreads();
#pragma unroll
    for (int i = 0; i < 4; i++) {
      int ch = tid + 256 * i;
      int r = ch >> 3, c8 = (ch & 7) * 8;
      *(short8*)&As[r * 72 + c8] = *(const short8*)(A + (size_t)(rowA0 + r) * lda + k0 + c8);
      *(short8*)&Bs[r * 72 + c8] = *(const short8*)(Bt + (size_t)(rowB0 + r) * ldb + k0 + c8);
    }
    __syncthreads();
#pragma unroll
    for (int kk = 0; kk < 64; kk += 32) {
      int kq = kk + quad * 8;
      short8 af[4], bfr[4];
#pragma unroll
      for (int t = 0; t < 4; t++) {
        af[t]  = *(const short8*)&As[(wm + t * 16 + rl) * 72 + kq];
        bfr[t] = *(const short8*)&Bs[(wn + t * 16 + rl) * 72 + kq];
      }
#pragma unroll
      for (int mt = 0; mt < 4; mt++)
#pragma unroll
        for (int nt = 0; nt < 4; nt++)
          acc[mt][nt] = __builtin_amdgcn_mfma_f32_16x16x32_bf16(af[mt], bfr[nt], acc[mt][nt], 0, 0, 0);
    }
  }
#pragma unroll
  for (int mt = 0; mt < 4; mt++)
#pragma unroll
    for (int nt = 0; nt < 4; nt++)
#pragma unroll
      for (int r = 0; r < 4; r++) {
        int row = rowA0 + wm + mt * 16 + quad * 4 + r;
        int col = rowB0 + wn + nt * 16 + rl;
        float* p = &C[(size_t)row * ldc + col];
        if (WMODE == 0) *p = acc[mt][nt][r];
        else if (WMODE == 1) *p += acc[mt][nt][r];
        else atomicAdd(p, acc[mt][nt][r]);
      }
}

// ---------------- fused K/V prep: null prepend, l2norm(k)*ks -> Kn[h][Lkp][64]; V transpose -> Vt[h][64][Lkp]
__global__ __launch_bounds__(256) void prep_kv(
    const float* __restrict__ kvb,   // k at kvb[(j-1)*3072 + h*64 + d], v at +1024
    const float* __restrict__ nullkv, const float* __restrict__ ks,
    u16* __restrict__ Kn, u16* __restrict__ Vt, int Lk, int Lkp)
{
  int h = blockIdx.y, j0 = blockIdx.x * 64;
  int tid = threadIdx.x, w = tid >> 6, d = tid & 63;
  float ksd = ks[d];
  // K phase: 16 keys per wave, full-wave l2norm per key
#pragma unroll 4
  for (int r = 0; r < 16; r++) {
    int j = j0 + w * 16 + r;
    float k = 0.f;
    if (j == 0) k = nullkv[h * 64 + d];
    else if (j < Lk) k = kvb[(size_t)(j - 1) * 3072 + h * 64 + d];
    float ssq = k * k;
#pragma unroll
    for (int ms = 1; ms < 64; ms <<= 1) ssq += __shfl_xor(ssq, ms, 64);
    float kn = k * (1.0f / fmaxf(sqrtf(ssq), 1e-12f)) * ksd;
    Kn[((size_t)h * Lkp + j) * 64 + d] = f2b(kn);
  }
  // V phase: transpose 64x64 via LDS
  __shared__ float tile[64][65];
  {
    int jl = tid >> 2, c16 = (tid & 3) * 16;
    int j = j0 + jl;
#pragma unroll
    for (int i4 = 0; i4 < 4; i4++) {
      float4 v = make_float4(0.f, 0.f, 0.f, 0.f);
      if (j == 0) v = *(const float4*)&nullkv[NHEAD * 64 + h * 64 + c16 + i4 * 4];
      else if (j < Lk) v = *(const float4*)&kvb[(size_t)(j - 1) * 3072 + 1024 + h * 64 + c16 + i4 * 4];
      tile[jl][c16 + i4 * 4] = v.x; tile[jl][c16 + i4 * 4 + 1] = v.y;
      tile[jl][c16 + i4 * 4 + 2] = v.z; tile[jl][c16 + i4 * 4 + 3] = v.w;
    }
  }
  __syncthreads();
  {
    int dd = tid >> 2, jc = (tid & 3) * 16;
    u16 pk[16];
#pragma unroll
    for (int i = 0; i < 16; i++) pk[i] = f2b(tile[jc + i][dd]);
    u16* op = Vt + ((size_t)h * 64 + dd) * Lkp + j0 + jc;
    *(short8*)&op[0] = *(short8*)&pk[0];
    *(short8*)&op[8] = *(short8*)&pk[8];
  }
}

// ---------------- MFMA flash attention, 4 waves doing in-block split-K over one 16-row q-tile.
// No running max needed (scores bounded by qs*ks*64 scale, exp fits f32), so split partials are
// exactly additive: each wave accumulates oacc = sum(p*v), lrow = sum(p) over k-tiles
// kt = w, w+4, ...; partials land in per-wave LDS buffers (deterministic, no atomics) and are
// combined + normalized once after a single barrier. Grid 1536 blocks x 4 waves, LDS ~27KB
// -> ~5 blocks/CU = ~20 waves/CU (vs old 6): latency-bound -> ~3.3x more TLP.
__global__ __launch_bounds__(256) void attn_mfma(
    const float* __restrict__ qkv, const float* __restrict__ qs,
    const u16* __restrict__ Kn, const u16* __restrict__ Vt,
    u16* __restrict__ Ob, int Lkp, int nk, float pad)
{
  __shared__ __align__(16) short Ps[4 * 16 * 72];
  __shared__ float Opart[4][16][68];
  __shared__ float Lpart[4][16];
  int tid = threadIdx.x, w = tid >> 6, lane = tid & 63;
  int rl = lane & 15, quad = lane >> 4;
  int b = blockIdx.x;
  int h = (b & 7) * 2 + ((b >> 3) & 1);   // XCD-clustered: XCD x -> heads {2x,2x+1}
  int qt = b >> 4;                         // 0..95
  int m0 = qt * 16;
  short* Pw = Ps + w * 16 * 72;

  // fused q l2norm * qs * 8 -> bf16 A-frags (all 4 waves redundantly; L2-hit, cheap)
  short8 aq[2];
  {
    const float* qp = qkv + (size_t)(m0 + rl) * 3072 + h * 64;
    float qv[16];
    float ssq = 0.f;
#pragma unroll
    for (int cb = 0; cb < 2; cb++) {
      float4 t0 = *(const float4*)&qp[cb * 32 + quad * 8];
      float4 t1 = *(const float4*)&qp[cb * 32 + quad * 8 + 4];
      qv[cb * 8 + 0] = t0.x; qv[cb * 8 + 1] = t0.y; qv[cb * 8 + 2] = t0.z; qv[cb * 8 + 3] = t0.w;
      qv[cb * 8 + 4] = t1.x; qv[cb * 8 + 5] = t1.y; qv[cb * 8 + 6] = t1.z; qv[cb * 8 + 7] = t1.w;
      ssq += t0.x * t0.x + t0.y * t0.y + t0.z * t0.z + t0.w * t0.w;
      ssq += t1.x * t1.x + t1.y * t1.y + t1.z * t1.z + t1.w * t1.w;
    }
    ssq += __shfl_xor(ssq, 16, 64);
    ssq += __shfl_xor(ssq, 32, 64);
    float inv = 8.0f / fmaxf(sqrtf(ssq), 1e-12f);
    u16 pk[16];
#pragma unroll
    for (int cb = 0; cb < 2; cb++) {
      float4 s0 = *(const float4*)&qs[cb * 32 + quad * 8];
      float4 s1 = *(const float4*)&qs[cb * 32 + quad * 8 + 4];
      pk[cb * 8 + 0] = f2b(qv[cb * 8 + 0] * inv * s0.x);
      pk[cb * 8 + 1] = f2b(qv[cb * 8 + 1] * inv * s0.y);
      pk[cb * 8 + 2] = f2b(qv[cb * 8 + 2] * inv * s0.z);
      pk[cb * 8 + 3] = f2b(qv[cb * 8 + 3] * inv * s0.w);
      pk[cb * 8 + 4] = f2b(qv[cb * 8 + 4] * inv * s1.x);
      pk[cb * 8 + 5] = f2b(qv[cb * 8 + 5] * inv * s1.y);
      pk[cb * 8 + 6] = f2b(qv[cb * 8 + 6] * inv * s1.z);
      pk[cb * 8 + 7] = f2b(qv[cb * 8 + 7] * inv * s1.w);
    }
    aq[0] = *(short8*)&pk[0];
    aq[1] = *(short8*)&pk[8];
  }

  const u16* Kh = Kn + (size_t)h * Lkp * 64;
  const u16* Vh = Vt + (size_t)h * 64 * Lkp;
  f32x4 oacc[4];
#pragma unroll
  for (int dt = 0; dt < 4; dt++) oacc[dt] = (f32x4)(0.f);
  float lrow[4] = {0.f, 0.f, 0.f, 0.f};

  for (int kt = w; kt < nk; kt += 4) {
    int j0 = kt * 64;
    short8 bk[4][2], bv[4][2];
#pragma unroll
    for (int nt = 0; nt < 4; nt++)
#pragma unroll
      for (int kc = 0; kc < 2; kc++)
        bk[nt][kc] = *(const short8*)(Kh + (size_t)(j0 + nt * 16 + rl) * 64 + kc * 32 + quad * 8);
#pragma unroll
    for (int dt = 0; dt < 4; dt++)
#pragma unroll
      for (int kc = 0; kc < 2; kc++)
        bv[dt][kc] = *(const short8*)(Vh + (size_t)(dt * 16 + rl) * Lkp + j0 + kc * 32 + quad * 8);

    f32x4 sacc[4];
#pragma unroll
    for (int nt = 0; nt < 4; nt++) sacc[nt] = (f32x4)(0.f);
#pragma unroll
    for (int kc = 0; kc < 2; kc++)
#pragma unroll
      for (int nt = 0; nt < 4; nt++)
        sacc[nt] = __builtin_amdgcn_mfma_f32_16x16x32_bf16(aq[kc], bk[nt][kc], sacc[nt], 0, 0, 0);

#pragma unroll
    for (int nt = 0; nt < 4; nt++)
#pragma unroll
      for (int r = 0; r < 4; r++) {
        float p = __expf(sacc[nt][r]);
        lrow[r] += p;
        Pw[(quad * 4 + r) * 72 + nt * 16 + rl] = (short)f2b(p);
      }
    __asm volatile("s_waitcnt lgkmcnt(0)" ::: "memory");
    short8 ap0 = *(const short8*)&Pw[rl * 72 + quad * 8];
    short8 ap1 = *(const short8*)&Pw[rl * 72 + 32 + quad * 8];
#pragma unroll
    for (int dt = 0; dt < 4; dt++) {
      oacc[dt] = __builtin_amdgcn_mfma_f32_16x16x32_bf16(ap0, bv[dt][0], oacc[dt], 0, 0, 0);
      oacc[dt] = __builtin_amdgcn_mfma_f32_16x16x32_bf16(ap1, bv[dt][1], oacc[dt], 0, 0, 0);
    }
  }
  // intra-wave row-sum reduce (within each 16-lane group)
#pragma unroll
  for (int r = 0; r < 4; r++) {
#pragma unroll
    for (int ms = 1; ms < 16; ms <<= 1) lrow[r] += __shfl_xor(lrow[r], ms, 64);
  }
  // deposit per-wave partials (deterministic, no atomics)
#pragma unroll
  for (int dt = 0; dt < 4; dt++)
#pragma unroll
    for (int r = 0; r < 4; r++)
      Opart[w][quad * 4 + r][dt * 16 + rl] = oacc[dt][r];
  if (rl == 0) {
#pragma unroll
    for (int r = 0; r < 4; r++) Lpart[w][quad * 4 + r] = lrow[r];
  }
  __syncthreads();
  // combine 4 wave-partials + normalize + store
  {
    int r = tid >> 4, c0 = (tid & 15) * 4;
    float l = Lpart[0][r] + Lpart[1][r] + Lpart[2][r] + Lpart[3][r] - pad;
    float invl = 1.0f / l;
    u16* op = Ob + (size_t)(m0 + r) * DMODEL + h * 64 + c0;
#pragma unroll
    for (int c = 0; c < 4; c++) {
      float v = Opart[0][r][c0 + c] + Opart[1][r][c0 + c] +
                Opart[2][r][c0 + c] + Opart[3][r][c0 + c];
      op[c] = f2b(v * invl);
    }
  }
}

// ---------------- fused GEGLU + LayerNorm -> bf16 (row = token) ----------------
__global__ __launch_bounds__(256) void geglu_ln(
    const float* __restrict__ h1, const float* __restrict__ g2, u16* __restrict__ Y)
{
  int row = blockIdx.x;
  const float* p = h1 + (size_t)row * FF1P;
  float act[11];
  float s = 0.f, sq = 0.f;
#pragma unroll
  for (int t = 0; t < 11; t++) {
    int i = threadIdx.x + t * 256;
    float v = 0.f;
    if (i < INNERD) {
      float a = p[i], gate = p[INNERD + i];
      float ge = 0.5f * a * (1.0f + erff(a * 0.70710678118654752f));
      v = gate * ge;
    }
    act[t] = v; s += v; sq += v * v;
  }
#pragma unroll
  for (int m = 1; m < 64; m <<= 1) { s += __shfl_xor(s, m, 64); sq += __shfl_xor(sq, m, 64); }
  __shared__ float red[2][4];
  int w = threadIdx.x >> 6;
  if ((threadIdx.x & 63) == 0) { red[0][w] = s; red[1][w] = sq; }
  __syncthreads();
  s = red[0][0] + red[0][1] + red[0][2] + red[0][3];
  sq = red[1][0] + red[1][1] + red[1][2] + red[1][3];
  float mean = s / INNERD;
  float var = sq / INNERD - mean * mean;
  float rstd = rsqrtf(var + 1e-5f);
  u16* y = Y + (size_t)row * INNERP;
#pragma unroll
  for (int t = 0; t < 11; t++) {
    int i = threadIdx.x + t * 256;
    if (i < INNERD) y[i] = f2b((act[t] - mean) * rstd * g2[i]);
  }
  if (threadIdx.x < INNERP - INNERD) y[INNERD + threadIdx.x] = 0;
}

// ---------------- host ----------------
extern "C" void kernel_launch(void* const* d_in, const int* in_sizes, int n_in,
                              void* d_out, int out_size, void* d_ws, size_t ws_size,
                              hipStream_t stream) {
  const int*   x        = (const int*)d_in[0];
  const int*   cond_ids = (const int*)d_in[1];
  const float* token_emb      = (const float*)d_in[2];
  const float* pos_emb        = (const float*)d_in[3];
  const float* cond_token_emb = (const float*)d_in[4];
  const float* cond_pos_emb   = (const float*)d_in[5];
  const float* sa_g   = (const float*)d_in[6];
  const float* sa_wq  = (const float*)d_in[7];
  const float* sa_wkv = (const float*)d_in[8];
  const float* sa_null= (const float*)d_in[9];
  const float* sa_qs  = (const float*)d_in[10];
  const float* sa_ks  = (const float*)d_in[11];
  const float* sa_wo  = (const float*)d_in[12];
  const float* ca_g   = (const float*)d_in[13];
  const float* ca_wq  = (const float*)d_in[14];
  const float* ca_wkv = (const float*)d_in[15];
  const float* ca_null= (const float*)d_in[16];
  const float* ca_qs  = (const float*)d_in[17];
  const float* ca_ks  = (const float*)d_in[18];
  const float* ca_wo  = (const float*)d_in[19];
  const float* ff_g1  = (const float*)d_in[20];
  const float* ff_w1  = (const float*)d_in[21];
  const float* ff_g2  = (const float*)d_in[22];
  const float* ff_w2  = (const float*)d_in[23];
  const float* final_g  = (const float*)d_in[24];
  const float* w_logits = (const float*)d_in[25];

  char* base = (char*)d_ws; size_t off = 0;
  auto alloc = [&](size_t bytes) -> void* {
    void* r = base + off; off = (off + bytes + 255) & ~(size_t)255; return r;
  };
  u16* sa_qkv_t = (u16*)alloc((size_t)4 * 3072 * 1024 * 2);
  u16* sa_wo_t  = (u16*)alloc((size_t)4 * 1024 * 1024 * 2);
  u16* ca_wq_t  = (u16*)alloc((size_t)4 * 1024 * 1024 * 2);
  u16* ca_wkv_t = (u16*)alloc((size_t)4 * 2048 * 1024 * 2);
  u16* ca_wo_t  = (u16*)alloc((size_t)4 * 1024 * 1024 * 2);
  u16* ff_w1_t  = (u16*)alloc((size_t)4 * FF1P * 1024 * 2);
  u16* ff_w2_t  = (u16*)alloc((size_t)4 * 1024 * INNERP * 2);
  u16* logits_t = (u16*)alloc((size_t)VOCAB * 1024 * 2);
  float* h    = (float*)alloc((size_t)N_TOK * DMODEL * 4);
  u16*   ctxb = (u16*)alloc((size_t)NCTX * DMODEL * 2);
  u16*   xnb  = (u16*)alloc((size_t)N_TOK * INNERP * 2);
  float* qkv  = (float*)alloc((size_t)N_TOK * 3072 * 4);
  u16*   Kn   = (u16*)alloc((size_t)NHEAD * 1600 * 64 * 2);
  u16*   Vt   = (u16*)alloc((size_t)NHEAD * 64 * 1600 * 2);
  u16*   ob   = (u16*)alloc((size_t)N_TOK * DMODEL * 2);
  float* h1   = (float*)alloc((size_t)N_TOK * FF1P * 4);
  (void)ws_size; (void)in_sizes; (void)n_in; (void)out_size;

  // weight convert+transpose (z = layer); grids in 64x64 tiles
  conv_t<<<dim3(16, 16, 4), 256, 0, stream>>>(sa_wq,  sa_qkv_t,              1024, 1024, 1024, 1024, 1024LL*1024, 3072LL*1024);
  conv_t<<<dim3(16, 32, 4), 256, 0, stream>>>(sa_wkv, sa_qkv_t + 1024*1024,  1024, 2048, 1024, 2048, 1024LL*2048, 3072LL*1024);
  conv_t<<<dim3(16, 16, 4), 256, 0, stream>>>(sa_wo,  sa_wo_t,               1024, 1024, 1024, 1024, 1024LL*1024, 1024LL*1024);
  conv_t<<<dim3(16, 16, 4), 256, 0, stream>>>(ca_wq,  ca_wq_t,               1024, 1024, 1024, 1024, 1024LL*1024, 1024LL*1024);
  conv_t<<<dim3(16, 32, 4), 256, 0, stream>>>(ca_wkv, ca_wkv_t,              1024, 2048, 1024, 2048, 1024LL*2048, 2048LL*1024);
  conv_t<<<dim3(16, 16, 4), 256, 0, stream>>>(ca_wo,  ca_wo_t,               1024, 1024, 1024, 1024, 1024LL*1024, 1024LL*1024);
  conv_t<<<dim3(16, 86, 4), 256, 0, stream>>>(ff_w1,  ff_w1_t,               1024, 5460, 1024, FF1P, 1024LL*5460, (long long)FF1P*1024);
  conv_t<<<dim3(43, 16, 4), 256, 0, stream>>>(ff_w2,  ff_w2_t,               INNERD, 1024, INNERP, 1024, (long long)INNERD*1024, 1024LL*INNERP);
  conv_t<<<dim3(16, 128, 1), 256, 0, stream>>>(w_logits, logits_t,           1024, VOCAB, 1024, VOCAB, 0, 0);

  // embeddings
  embed_img<<<dim3(N_TOK), dim3(256), 0, stream>>>(x, token_emb, pos_emb, h);
  embed_ctx<<<dim3(NCTX), dim3(256), 0, stream>>>(cond_ids, cond_token_emb, cond_pos_emb, ctxb);

  for (int l = 0; l < 4; l++) {
    const u16* sqkv = sa_qkv_t + (size_t)l * 3072 * 1024;
    const u16* swo  = sa_wo_t  + (size_t)l * 1024 * 1024;
    const u16* cwq  = ca_wq_t  + (size_t)l * 1024 * 1024;
    const u16* cwkv = ca_wkv_t + (size_t)l * 2048 * 1024;
    const u16* cwo  = ca_wo_t  + (size_t)l * 1024 * 1024;
    const u16* fw1  = ff_w1_t  + (size_t)l * FF1P * 1024;
    const u16* fw2  = ff_w2_t  + (size_t)l * 1024 * INNERP;

    // ---- self-attention ----
    ln_bf16<<<dim3(N_TOK), dim3(256), 0, stream>>>(h, DMODEL, sa_g + l * DMODEL, xnb, DMODEL, DMODEL, DMODEL);
    gemm_bt<0, 1><<<dim3(12, 24, 1), dim3(256), 0, stream>>>(xnb, sqkv, qkv, 3072, N_TOK, 3072, 1024, 1024, 1024);
    prep_kv<<<dim3(25, NHEAD), dim3(256), 0, stream>>>(qkv + 1024, sa_null + l * 2048, sa_ks + l * 64, Kn, Vt, 1537, 1600);
    attn_mfma<<<dim3(1536), dim3(256), 0, stream>>>(qkv, sa_qs + l * 64, Kn, Vt, ob, 1600, 25, 63.0f);
    gemm_bt<2, 4><<<dim3(12, 8, 4), dim3(256), 0, stream>>>(ob, swo, h, 1024, N_TOK, 1024, 1024, 1024, 1024);

    // ---- cross-attention ----
    ln_bf16<<<dim3(N_TOK), dim3(256), 0, stream>>>(h, DMODEL, ca_g + l * DMODEL, xnb, DMODEL, DMODEL, DMODEL);
    hipMemsetAsync(qkv, 0, (size_t)N_TOK * 3072 * 4, stream);
    gemm_bt<2, 4><<<dim3(12, 8, 4), dim3(256), 0, stream>>>(xnb, cwq, qkv, 3072, N_TOK, 1024, 1024, 1024, 1024);
    gemm_bt<2, 4><<<dim3(4, 16, 4), dim3(256), 0, stream>>>(ctxb, cwkv, qkv + 1024, 3072, NCTX, 2048, 1024, 1024, 1024);
    prep_kv<<<dim3(9, NHEAD), dim3(256), 0, stream>>>(qkv + 1024, ca_null + l * 2048, ca_ks + l * 64, Kn, Vt, 513, 576);
    attn_mfma<<<dim3(1536), dim3(256), 0, stream>>>(qkv, ca_qs + l * 64, Kn, Vt, ob, 576, 9, 63.0f);
    gemm_bt<2, 4><<<dim3(12, 8, 4), dim3(256), 0, stream>>>(ob, cwo, h, 1024, N_TOK, 1024, 1024, 1024, 1024);

    // ---- GEGLU feedforward ----
    ln_bf16<<<dim3(N_TOK), dim3(256), 0, stream>>>(h, DMODEL, ff_g1 + l * DMODEL, xnb, DMODEL, DMODEL, DMODEL);
    gemm_bt<0, 1><<<dim3(12, 43, 1), dim3(256), 0, stream>>>(xnb, fw1, h1, FF1P, N_TOK, FF1P, 1024, 1024, 1024);
    geglu_ln<<<dim3(N_TOK), dim3(256), 0, stream>>>(h1, ff_g2 + l * INNERD, xnb);
    gemm_bt<2, 4><<<dim3(12, 8, 4), dim3(256), 0, stream>>>(xnb, fw2, h, 1024, N_TOK, 1024, INNERP, INNERP, INNERP);
  }

  // ---- final LN + logits ----
  ln_bf16<<<dim3(N_TOK), dim3(256), 0, stream>>>(h, DMODEL, final_g, xnb, DMODEL, DMODEL, DMODEL);
  gemm_bt<0, 1><<<dim3(12, 64, 1), dim3(256), 0, stream>>>(xnb, logits_t, (float*)d_out, VOCAB, N_TOK, VOCAB, 1024, 1024, 1024);
}

// Round 3
// 1688.113 us; speedup vs baseline: 1.1303x; 1.1303x over previous
//
#include <hip/hip_runtime.h>

// ---------------- types / helpers ----------------
typedef __attribute__((ext_vector_type(8))) short short8;
typedef __attribute__((ext_vector_type(4))) float f32x4;
typedef unsigned short u16;

#define N_TOK   1536
#define DMODEL  1024
#define NHEAD   16
#define DHEAD   64
#define NCTX    512
#define INNERD  2730
#define INNERP  2752   // K-padded inner
#define FF1P    5504   // N-padded 2*inner
#define VOCAB   8192

__device__ __forceinline__ u16 f2b(float f) {
  union { float f; unsigned u; } v; v.f = f;
  unsigned r = (v.u >> 16) & 1u;
  return (u16)((v.u + 0x7fffu + r) >> 16);
}

// ---------------- weight convert+transpose: f32 [z][K][Nw] -> bf16 [z][..][Kpad], out[n][k]=in[k][n]
__global__ __launch_bounds__(256) void conv_t(
    const float* __restrict__ in, u16* __restrict__ out,
    int K, int Nw, int Kpad, int Nbound, long long zin, long long zout)
{
  const float* inl = in + (size_t)blockIdx.z * zin;
  u16* outl = out + (size_t)blockIdx.z * zout;
  __shared__ float tile[64][65];
  int k0 = blockIdx.x * 64, n0 = blockIdx.y * 64;
  int tid = threadIdx.x;
  {
    int r = tid >> 4, c4 = (tid & 15) * 4;
#pragma unroll
    for (int j = 0; j < 4; j++) {
      int k = k0 + r + j * 16;
      float4 v = make_float4(0.f, 0.f, 0.f, 0.f);
      if (k < K && (n0 + c4) < Nw) v = *(const float4*)&inl[(size_t)k * Nw + n0 + c4];
      tile[r + j * 16][c4] = v.x; tile[r + j * 16][c4 + 1] = v.y;
      tile[r + j * 16][c4 + 2] = v.z; tile[r + j * 16][c4 + 3] = v.w;
    }
  }
  __syncthreads();
  {
    int nl = tid >> 2, kc = (tid & 3) * 16;
    int n = n0 + nl;
    if (n < Nbound) {
      u16 pk[16];
#pragma unroll
      for (int i = 0; i < 16; i++) pk[i] = f2b(tile[kc + i][nl]);
      u16* op = outl + (size_t)n * Kpad + k0 + kc;
      *(short8*)&op[0] = *(short8*)&pk[0];
      *(short8*)&op[8] = *(short8*)&pk[8];
    }
  }
}

// ---------------- embeddings ----------------
__global__ void embed_img(const int* __restrict__ x, const float* __restrict__ temb,
                          const float* __restrict__ pemb, float* __restrict__ h) {
  int n = blockIdx.x; int tok = x[n]; int d4 = threadIdx.x;
  float4 a = *(const float4*)&temb[(size_t)tok * DMODEL + d4 * 4];
  float4 b = *(const float4*)&pemb[(size_t)n * DMODEL + d4 * 4];
  float4 o; o.x = a.x + b.x; o.y = a.y + b.y; o.z = a.z + b.z; o.w = a.w + b.w;
  *(float4*)&h[(size_t)n * DMODEL + d4 * 4] = o;
}

__global__ void embed_ctx(const int* __restrict__ ids, const float* __restrict__ temb,
                          const float* __restrict__ pemb, u16* __restrict__ ctxb) {
  int n = blockIdx.x; int tok = ids[n]; int d4 = threadIdx.x;
  float4 a = *(const float4*)&temb[(size_t)tok * DMODEL + d4 * 4];
  float4 b = *(const float4*)&pemb[(size_t)n * DMODEL + d4 * 4];
  u16* o = ctxb + (size_t)n * DMODEL + d4 * 4;
  o[0] = f2b(a.x + b.x); o[1] = f2b(a.y + b.y); o[2] = f2b(a.z + b.z); o[3] = f2b(a.w + b.w);
}

// ---------------- LayerNorm -> bf16 ----------------
__global__ __launch_bounds__(256) void ln_bf16(
    const float* __restrict__ X, int ldin, const float* __restrict__ g,
    u16* __restrict__ Y, int ldout, int C, int Cpad)
{
  int row = blockIdx.x;
  const float* x = X + (size_t)row * ldin;
  float s = 0.f, sq = 0.f;
  for (int ci = threadIdx.x; ci < C; ci += 256) { float v = x[ci]; s += v; sq += v * v; }
#pragma unroll
  for (int m = 1; m < 64; m <<= 1) { s += __shfl_xor(s, m, 64); sq += __shfl_xor(sq, m, 64); }
  __shared__ float red[2][4];
  int w = threadIdx.x >> 6;
  if ((threadIdx.x & 63) == 0) { red[0][w] = s; red[1][w] = sq; }
  __syncthreads();
  s = red[0][0] + red[0][1] + red[0][2] + red[0][3];
  sq = red[1][0] + red[1][1] + red[1][2] + red[1][3];
  float mean = s / C;
  float var = sq / C - mean * mean;
  float rstd = rsqrtf(var + 1e-5f);
  u16* y = Y + (size_t)row * ldout;
  for (int ci = threadIdx.x; ci < C; ci += 256) y[ci] = f2b((x[ci] - mean) * rstd * g[ci]);
  for (int ci = C + threadIdx.x; ci < Cpad; ci += 256) y[ci] = 0;
}

// ---------------- GEMM: C(M,N) = A(M,K)bf16 @ Bt(N,K)bf16, 128x128 tile, BK=64 ----------------
template <int WMODE, int NSPLIT>
__global__ __launch_bounds__(256) void gemm_bt(
    const u16* __restrict__ A, const u16* __restrict__ Bt,
    float* __restrict__ C, int ldc, int M, int N, int K, int lda, int ldb)
{
  __shared__ __align__(16) short As[128 * 72];
  __shared__ __align__(16) short Bs[128 * 72];
  int tid = threadIdx.x;
  int bm = blockIdx.x, bn = blockIdx.y;
  int lane = tid & 63, w = tid >> 6;
  int wm = (w >> 1) * 64, wn = (w & 1) * 64;
  int rl = lane & 15, quad = lane >> 4;
  f32x4 acc[4][4];
#pragma unroll
  for (int i = 0; i < 4; i++)
#pragma unroll
    for (int j = 0; j < 4; j++) acc[i][j] = (f32x4)(0.f);
  const int rowA0 = bm * 128, rowB0 = bn * 128;
  int tiles = K >> 6;
  int t0 = (tiles * blockIdx.z) / NSPLIT, t1 = (tiles * (blockIdx.z + 1)) / NSPLIT;

  for (int kt = t0; kt < t1; kt++) {
    int k0 = kt * 64;
    __syncthreads();
#pragma unroll
    for (int i = 0; i < 4; i++) {
      int ch = tid + 256 * i;
      int r = ch >> 3, c8 = (ch & 7) * 8;
      *(short8*)&As[r * 72 + c8] = *(const short8*)(A + (size_t)(rowA0 + r) * lda + k0 + c8);
      *(short8*)&Bs[r * 72 + c8] = *(const short8*)(Bt + (size_t)(rowB0 + r) * ldb + k0 + c8);
    }
    __syncthreads();
#pragma unroll
    for (int kk = 0; kk < 64; kk += 32) {
      int kq = kk + quad * 8;
      short8 af[4], bfr[4];
#pragma unroll
      for (int t = 0; t < 4; t++) {
        af[t]  = *(const short8*)&As[(wm + t * 16 + rl) * 72 + kq];
        bfr[t] = *(const short8*)&Bs[(wn + t * 16 + rl) * 72 + kq];
      }
#pragma unroll
      for (int mt = 0; mt < 4; mt++)
#pragma unroll
        for (int nt = 0; nt < 4; nt++)
          acc[mt][nt] = __builtin_amdgcn_mfma_f32_16x16x32_bf16(af[mt], bfr[nt], acc[mt][nt], 0, 0, 0);
    }
  }
#pragma unroll
  for (int mt = 0; mt < 4; mt++)
#pragma unroll
    for (int nt = 0; nt < 4; nt++)
#pragma unroll
      for (int r = 0; r < 4; r++) {
        int row = rowA0 + wm + mt * 16 + quad * 4 + r;
        int col = rowB0 + wn + nt * 16 + rl;
        float* p = &C[(size_t)row * ldc + col];
        if (WMODE == 0) *p = acc[mt][nt][r];
        else if (WMODE == 1) *p += acc[mt][nt][r];
        else atomicAdd(p, acc[mt][nt][r]);
      }
}

// ---------------- fused K/V prep: null prepend, l2norm(k)*ks -> Kn[h][Lkp][64]; V transpose -> Vt[h][64][Lkp]
__global__ __launch_bounds__(256) void prep_kv(
    const float* __restrict__ kvb,
    const float* __restrict__ nullkv, const float* __restrict__ ks,
    u16* __restrict__ Kn, u16* __restrict__ Vt, int Lk, int Lkp)
{
  int h = blockIdx.y, j0 = blockIdx.x * 64;
  int tid = threadIdx.x, w = tid >> 6, d = tid & 63;
  float ksd = ks[d];
#pragma unroll 4
  for (int r = 0; r < 16; r++) {
    int j = j0 + w * 16 + r;
    float k = 0.f;
    if (j == 0) k = nullkv[h * 64 + d];
    else if (j < Lk) k = kvb[(size_t)(j - 1) * 3072 + h * 64 + d];
    float ssq = k * k;
#pragma unroll
    for (int ms = 1; ms < 64; ms <<= 1) ssq += __shfl_xor(ssq, ms, 64);
    float kn = k * (1.0f / fmaxf(sqrtf(ssq), 1e-12f)) * ksd;
    Kn[((size_t)h * Lkp + j) * 64 + d] = f2b(kn);
  }
  __shared__ float tile[64][65];
  {
    int jl = tid >> 2, c16 = (tid & 3) * 16;
    int j = j0 + jl;
#pragma unroll
    for (int i4 = 0; i4 < 4; i4++) {
      float4 v = make_float4(0.f, 0.f, 0.f, 0.f);
      if (j == 0) v = *(const float4*)&nullkv[NHEAD * 64 + h * 64 + c16 + i4 * 4];
      else if (j < Lk) v = *(const float4*)&kvb[(size_t)(j - 1) * 3072 + 1024 + h * 64 + c16 + i4 * 4];
      tile[jl][c16 + i4 * 4] = v.x; tile[jl][c16 + i4 * 4 + 1] = v.y;
      tile[jl][c16 + i4 * 4 + 2] = v.z; tile[jl][c16 + i4 * 4 + 3] = v.w;
    }
  }
  __syncthreads();
  {
    int dd = tid >> 2, jc = (tid & 3) * 16;
    u16 pk[16];
#pragma unroll
    for (int i = 0; i < 16; i++) pk[i] = f2b(tile[jc + i][dd]);
    u16* op = Vt + ((size_t)h * 64 + dd) * Lkp + j0 + jc;
    *(short8*)&op[0] = *(short8*)&pk[0];
    *(short8*)&op[8] = *(short8*)&pk[8];
  }
}

// ---------------- MFMA flash attention, block-cooperative LDS staging.
// Block = 64 q-rows x 1 head x half-of-K (2-way split-K across blocks): grid 768 = 3 blocks/CU,
// 4 waves each owning 16 q-rows. K/V 64-key tiles staged ONCE per block into double-buffered
// LDS (XOR-swizzled: col16 ^= row&7 -> conflict-free ds_read_b128 fragments), via coalesced
// register staging issued one tile ahead (load latency hides under compute). Cuts L2 K/V
// traffic 4x vs per-wave gathers and makes lines fully utilized. Partials (O, sum p) to global
// scratch; attn_fin combines the 2 K-halves + normalizes.
__global__ __launch_bounds__(256) void attn_mfma(
    const float* __restrict__ qkv, const float* __restrict__ qs,
    const u16* __restrict__ Kn, const u16* __restrict__ Vt,
    float* __restrict__ Opar, float* __restrict__ Lpar, int Lkp, int nk)
{
  __shared__ __align__(16) u16 Kt[2][64 * 64];
  __shared__ __align__(16) u16 Vs[2][64 * 64];
  __shared__ __align__(16) short Ps[4 * 16 * 72];
  int tid = threadIdx.x, w = tid >> 6, lane = tid & 63;
  int rl = lane & 15, quad = lane >> 4;
  int b = blockIdx.x;
  int h = (b & 7) * 2 + ((b >> 3) & 1);   // XCD-clustered: XCD x -> heads {2x,2x+1}
  int rest = b >> 4;                       // 0..47
  int qg = rest >> 1, ks = rest & 1;
  int m0 = qg * 64 + w * 16;               // this wave's 16 q-rows
  int t0 = (nk * ks) >> 1, t1 = (nk * (ks + 1)) >> 1;
  short* Pw = Ps + w * 16 * 72;

  // fused q l2norm * qs * 8 -> bf16 A-frags (each wave: its own 16 rows)
  short8 aq[2];
  {
    const float* qp = qkv + (size_t)(m0 + rl) * 3072 + h * 64;
    float qv[16];
    float ssq = 0.f;
#pragma unroll
    for (int cb = 0; cb < 2; cb++) {
      float4 v0 = *(const float4*)&qp[cb * 32 + quad * 8];
      float4 v1 = *(const float4*)&qp[cb * 32 + quad * 8 + 4];
      qv[cb * 8 + 0] = v0.x; qv[cb * 8 + 1] = v0.y; qv[cb * 8 + 2] = v0.z; qv[cb * 8 + 3] = v0.w;
      qv[cb * 8 + 4] = v1.x; qv[cb * 8 + 5] = v1.y; qv[cb * 8 + 6] = v1.z; qv[cb * 8 + 7] = v1.w;
      ssq += v0.x * v0.x + v0.y * v0.y + v0.z * v0.z + v0.w * v0.w;
      ssq += v1.x * v1.x + v1.y * v1.y + v1.z * v1.z + v1.w * v1.w;
    }
    ssq += __shfl_xor(ssq, 16, 64);
    ssq += __shfl_xor(ssq, 32, 64);
    float inv = 8.0f / fmaxf(sqrtf(ssq), 1e-12f);
    u16 pk[16];
#pragma unroll
    for (int cb = 0; cb < 2; cb++) {
      float4 s0 = *(const float4*)&qs[cb * 32 + quad * 8];
      float4 s1 = *(const float4*)&qs[cb * 32 + quad * 8 + 4];
      pk[cb * 8 + 0] = f2b(qv[cb * 8 + 0] * inv * s0.x);
      pk[cb * 8 + 1] = f2b(qv[cb * 8 + 1] * inv * s0.y);
      pk[cb * 8 + 2] = f2b(qv[cb * 8 + 2] * inv * s0.z);
      pk[cb * 8 + 3] = f2b(qv[cb * 8 + 3] * inv * s0.w);
      pk[cb * 8 + 4] = f2b(qv[cb * 8 + 4] * inv * s1.x);
      pk[cb * 8 + 5] = f2b(qv[cb * 8 + 5] * inv * s1.y);
      pk[cb * 8 + 6] = f2b(qv[cb * 8 + 6] * inv * s1.z);
      pk[cb * 8 + 7] = f2b(qv[cb * 8 + 7] * inv * s1.w);
    }
    aq[0] = *(short8*)&pk[0];
    aq[1] = *(short8*)&pk[8];
  }

  const u16* Kh = Kn + (size_t)h * Lkp * 64;
  const u16* Vh = Vt + (size_t)h * 64 * Lkp;

  // staging geometry: each wave stages 2KB K + 2KB V per tile (rows w*16 .. w*16+15)
  int srow0 = w * 16 + (lane >> 3);   // + c*8
  int scol = (lane & 7) * 8;          // u16 units (16B chunk index * 8)

  short8 stg[4];
  {
    int j0 = t0 * 64;
#pragma unroll
    for (int c = 0; c < 2; c++) {
      int row = srow0 + c * 8;
      stg[c]     = *(const short8*)(Kh + (size_t)(j0 + row) * 64 + scol);
      stg[2 + c] = *(const short8*)(Vh + (size_t)row * Lkp + j0 + scol);
    }
  }

  f32x4 oacc[4];
#pragma unroll
  for (int dt = 0; dt < 4; dt++) oacc[dt] = (f32x4)(0.f);
  float lrow[4] = {0.f, 0.f, 0.f, 0.f};

  for (int kt = t0; kt < t1; kt++) {
    int buf = kt & 1;
    u16* KtB = Kt[buf];
    u16* VsB = Vs[buf];
    // write staged regs -> LDS with XOR swizzle (col16 ^= row&7)
#pragma unroll
    for (int c = 0; c < 2; c++) {
      int row = srow0 + c * 8;
      int cs = scol ^ ((row & 7) * 8);
      *(short8*)&KtB[row * 64 + cs] = stg[c];
      *(short8*)&VsB[row * 64 + cs] = stg[2 + c];
    }
    // issue next tile's loads (fly during compute)
    if (kt + 1 < t1) {
      int j0 = (kt + 1) * 64;
#pragma unroll
      for (int c = 0; c < 2; c++) {
        int row = srow0 + c * 8;
        stg[c]     = *(const short8*)(Kh + (size_t)(j0 + row) * 64 + scol);
        stg[2 + c] = *(const short8*)(Vh + (size_t)row * Lkp + j0 + scol);
      }
    }
    // drain own LDS writes (NOT the global loads), then block barrier
    __asm volatile("s_waitcnt lgkmcnt(0)" ::: "memory");
    __builtin_amdgcn_s_barrier();
    __asm volatile("" ::: "memory");

    // ---- QK^T from swizzled LDS (row&7 == rl&7 for frag rows) ----
    f32x4 sacc[4];
#pragma unroll
    for (int nt = 0; nt < 4; nt++) sacc[nt] = (f32x4)(0.f);
#pragma unroll
    for (int kc = 0; kc < 2; kc++)
#pragma unroll
      for (int nt = 0; nt < 4; nt++) {
        short8 bkf = *(const short8*)&KtB[(nt * 16 + rl) * 64 + (((kc * 4 + quad) ^ (rl & 7)) * 8)];
        sacc[nt] = __builtin_amdgcn_mfma_f32_16x16x32_bf16(aq[kc], bkf, sacc[nt], 0, 0, 0);
      }

#pragma unroll
    for (int nt = 0; nt < 4; nt++)
#pragma unroll
      for (int r = 0; r < 4; r++) {
        float p = __expf(sacc[nt][r]);
        lrow[r] += p;
        Pw[(quad * 4 + r) * 72 + nt * 16 + rl] = (short)f2b(p);
      }
    __asm volatile("s_waitcnt lgkmcnt(0)" ::: "memory");
    short8 ap0 = *(const short8*)&Pw[rl * 72 + quad * 8];
    short8 ap1 = *(const short8*)&Pw[rl * 72 + 32 + quad * 8];
#pragma unroll
    for (int dt = 0; dt < 4; dt++) {
      short8 bv0 = *(const short8*)&VsB[(dt * 16 + rl) * 64 + ((quad ^ (rl & 7)) * 8)];
      short8 bv1 = *(const short8*)&VsB[(dt * 16 + rl) * 64 + (((4 + quad) ^ (rl & 7)) * 8)];
      oacc[dt] = __builtin_amdgcn_mfma_f32_16x16x32_bf16(ap0, bv0, oacc[dt], 0, 0, 0);
      oacc[dt] = __builtin_amdgcn_mfma_f32_16x16x32_bf16(ap1, bv1, oacc[dt], 0, 0, 0);
    }
    __asm volatile("" ::: "memory");
  }

  // row-sum reduce within 16-lane groups
#pragma unroll
  for (int r = 0; r < 4; r++) {
#pragma unroll
    for (int ms = 1; ms < 16; ms <<= 1) lrow[r] += __shfl_xor(lrow[r], ms, 64);
  }
  // store split-K partials
  float* Op = Opar + ((size_t)ks * N_TOK + m0) * DMODEL + h * 64;
#pragma unroll
  for (int dt = 0; dt < 4; dt++)
#pragma unroll
    for (int r = 0; r < 4; r++)
      Op[(size_t)(quad * 4 + r) * DMODEL + dt * 16 + rl] = oacc[dt][r];
  if (rl == 0) {
#pragma unroll
    for (int r = 0; r < 4; r++)
      Lpar[((size_t)ks * N_TOK + m0 + quad * 4 + r) * 16 + h] = lrow[r];
  }
}

// ---------------- combine split-K partials + normalize -> bf16 ----------------
__global__ __launch_bounds__(256) void attn_fin(
    const float* __restrict__ Opar, const float* __restrict__ Lpar,
    u16* __restrict__ Ob, float pad)
{
  int m = blockIdx.x, t = threadIdx.x;
  int c = t * 4, hh = t >> 4;
  float l = Lpar[(size_t)m * 16 + hh] + Lpar[(size_t)(N_TOK + m) * 16 + hh] - pad;
  float inv = 1.0f / l;
  float4 a = *(const float4*)(Opar + (size_t)m * DMODEL + c);
  float4 d = *(const float4*)(Opar + (size_t)(N_TOK + m) * DMODEL + c);
  u16* op = Ob + (size_t)m * DMODEL + c;
  op[0] = f2b((a.x + d.x) * inv);
  op[1] = f2b((a.y + d.y) * inv);
  op[2] = f2b((a.z + d.z) * inv);
  op[3] = f2b((a.w + d.w) * inv);
}

// ---------------- fused GEGLU + LayerNorm -> bf16 (row = token) ----------------
__global__ __launch_bounds__(256) void geglu_ln(
    const float* __restrict__ h1, const float* __restrict__ g2, u16* __restrict__ Y)
{
  int row = blockIdx.x;
  const float* p = h1 + (size_t)row * FF1P;
  float act[11];
  float s = 0.f, sq = 0.f;
#pragma unroll
  for (int t = 0; t < 11; t++) {
    int i = threadIdx.x + t * 256;
    float v = 0.f;
    if (i < INNERD) {
      float a = p[i], gate = p[INNERD + i];
      float ge = 0.5f * a * (1.0f + erff(a * 0.70710678118654752f));
      v = gate * ge;
    }
    act[t] = v; s += v; sq += v * v;
  }
#pragma unroll
  for (int m = 1; m < 64; m <<= 1) { s += __shfl_xor(s, m, 64); sq += __shfl_xor(sq, m, 64); }
  __shared__ float red[2][4];
  int w = threadIdx.x >> 6;
  if ((threadIdx.x & 63) == 0) { red[0][w] = s; red[1][w] = sq; }
  __syncthreads();
  s = red[0][0] + red[0][1] + red[0][2] + red[0][3];
  sq = red[1][0] + red[1][1] + red[1][2] + red[1][3];
  float mean = s / INNERD;
  float var = sq / INNERD - mean * mean;
  float rstd = rsqrtf(var + 1e-5f);
  u16* y = Y + (size_t)row * INNERP;
#pragma unroll
  for (int t = 0; t < 11; t++) {
    int i = threadIdx.x + t * 256;
    if (i < INNERD) y[i] = f2b((act[t] - mean) * rstd * g2[i]);
  }
  if (threadIdx.x < INNERP - INNERD) y[INNERD + threadIdx.x] = 0;
}

// ---------------- host ----------------
extern "C" void kernel_launch(void* const* d_in, const int* in_sizes, int n_in,
                              void* d_out, int out_size, void* d_ws, size_t ws_size,
                              hipStream_t stream) {
  const int*   x        = (const int*)d_in[0];
  const int*   cond_ids = (const int*)d_in[1];
  const float* token_emb      = (const float*)d_in[2];
  const float* pos_emb        = (const float*)d_in[3];
  const float* cond_token_emb = (const float*)d_in[4];
  const float* cond_pos_emb   = (const float*)d_in[5];
  const float* sa_g   = (const float*)d_in[6];
  const float* sa_wq  = (const float*)d_in[7];
  const float* sa_wkv = (const float*)d_in[8];
  const float* sa_null= (const float*)d_in[9];
  const float* sa_qs  = (const float*)d_in[10];
  const float* sa_ks  = (const float*)d_in[11];
  const float* sa_wo  = (const float*)d_in[12];
  const float* ca_g   = (const float*)d_in[13];
  const float* ca_wq  = (const float*)d_in[14];
  const float* ca_wkv = (const float*)d_in[15];
  const float* ca_null= (const float*)d_in[16];
  const float* ca_qs  = (const float*)d_in[17];
  const float* ca_ks  = (const float*)d_in[18];
  const float* ca_wo  = (const float*)d_in[19];
  const float* ff_g1  = (const float*)d_in[20];
  const float* ff_w1  = (const float*)d_in[21];
  const float* ff_g2  = (const float*)d_in[22];
  const float* ff_w2  = (const float*)d_in[23];
  const float* final_g  = (const float*)d_in[24];
  const float* w_logits = (const float*)d_in[25];

  char* base = (char*)d_ws; size_t off = 0;
  auto alloc = [&](size_t bytes) -> void* {
    void* r = base + off; off = (off + bytes + 255) & ~(size_t)255; return r;
  };
  u16* sa_qkv_t = (u16*)alloc((size_t)4 * 3072 * 1024 * 2);
  u16* sa_wo_t  = (u16*)alloc((size_t)4 * 1024 * 1024 * 2);
  u16* ca_wq_t  = (u16*)alloc((size_t)4 * 1024 * 1024 * 2);
  u16* ca_wkv_t = (u16*)alloc((size_t)4 * 2048 * 1024 * 2);
  u16* ca_wo_t  = (u16*)alloc((size_t)4 * 1024 * 1024 * 2);
  u16* ff_w1_t  = (u16*)alloc((size_t)4 * FF1P * 1024 * 2);
  u16* ff_w2_t  = (u16*)alloc((size_t)4 * 1024 * INNERP * 2);
  u16* logits_t = (u16*)alloc((size_t)VOCAB * 1024 * 2);
  float* h    = (float*)alloc((size_t)N_TOK * DMODEL * 4);
  u16*   ctxb = (u16*)alloc((size_t)NCTX * DMODEL * 2);
  u16*   xnb  = (u16*)alloc((size_t)N_TOK * INNERP * 2);
  float* qkv  = (float*)alloc((size_t)N_TOK * 3072 * 4);
  u16*   Kn   = (u16*)alloc((size_t)NHEAD * 1600 * 64 * 2);
  u16*   Vt   = (u16*)alloc((size_t)NHEAD * 64 * 1600 * 2);
  u16*   ob   = (u16*)alloc((size_t)N_TOK * DMODEL * 2);
  float* h1   = (float*)alloc((size_t)N_TOK * FF1P * 4);
  // attn split-K scratch reuses h1 (h1 is dead during attention phases)
  float* Opar = (float*)h1;                              // [2][N_TOK][DMODEL] f32
  float* Lpar = Opar + (size_t)2 * N_TOK * DMODEL;       // [2][N_TOK][16] f32
  (void)ws_size; (void)in_sizes; (void)n_in; (void)out_size;

  // weight convert+transpose (z = layer); grids in 64x64 tiles
  conv_t<<<dim3(16, 16, 4), 256, 0, stream>>>(sa_wq,  sa_qkv_t,              1024, 1024, 1024, 1024, 1024LL*1024, 3072LL*1024);
  conv_t<<<dim3(16, 32, 4), 256, 0, stream>>>(sa_wkv, sa_qkv_t + 1024*1024,  1024, 2048, 1024, 2048, 1024LL*2048, 3072LL*1024);
  conv_t<<<dim3(16, 16, 4), 256, 0, stream>>>(sa_wo,  sa_wo_t,               1024, 1024, 1024, 1024, 1024LL*1024, 1024LL*1024);
  conv_t<<<dim3(16, 16, 4), 256, 0, stream>>>(ca_wq,  ca_wq_t,               1024, 1024, 1024, 1024, 1024LL*1024, 1024LL*1024);
  conv_t<<<dim3(16, 32, 4), 256, 0, stream>>>(ca_wkv, ca_wkv_t,              1024, 2048, 1024, 2048, 1024LL*2048, 2048LL*1024);
  conv_t<<<dim3(16, 16, 4), 256, 0, stream>>>(ca_wo,  ca_wo_t,               1024, 1024, 1024, 1024, 1024LL*1024, 1024LL*1024);
  conv_t<<<dim3(16, 86, 4), 256, 0, stream>>>(ff_w1,  ff_w1_t,               1024, 5460, 1024, FF1P, 1024LL*5460, (long long)FF1P*1024);
  conv_t<<<dim3(43, 16, 4), 256, 0, stream>>>(ff_w2,  ff_w2_t,               INNERD, 1024, INNERP, 1024, (long long)INNERD*1024, 1024LL*INNERP);
  conv_t<<<dim3(16, 128, 1), 256, 0, stream>>>(w_logits, logits_t,           1024, VOCAB, 1024, VOCAB, 0, 0);

  // embeddings
  embed_img<<<dim3(N_TOK), dim3(256), 0, stream>>>(x, token_emb, pos_emb, h);
  embed_ctx<<<dim3(NCTX), dim3(256), 0, stream>>>(cond_ids, cond_token_emb, cond_pos_emb, ctxb);

  for (int l = 0; l < 4; l++) {
    const u16* sqkv = sa_qkv_t + (size_t)l * 3072 * 1024;
    const u16* swo  = sa_wo_t  + (size_t)l * 1024 * 1024;
    const u16* cwq  = ca_wq_t  + (size_t)l * 1024 * 1024;
    const u16* cwkv = ca_wkv_t + (size_t)l * 2048 * 1024;
    const u16* cwo  = ca_wo_t  + (size_t)l * 1024 * 1024;
    const u16* fw1  = ff_w1_t  + (size_t)l * FF1P * 1024;
    const u16* fw2  = ff_w2_t  + (size_t)l * 1024 * INNERP;

    // ---- self-attention ----
    ln_bf16<<<dim3(N_TOK), dim3(256), 0, stream>>>(h, DMODEL, sa_g + l * DMODEL, xnb, DMODEL, DMODEL, DMODEL);
    gemm_bt<0, 1><<<dim3(12, 24, 1), dim3(256), 0, stream>>>(xnb, sqkv, qkv, 3072, N_TOK, 3072, 1024, 1024, 1024);
    prep_kv<<<dim3(25, NHEAD), dim3(256), 0, stream>>>(qkv + 1024, sa_null + l * 2048, sa_ks + l * 64, Kn, Vt, 1537, 1600);
    attn_mfma<<<dim3(768), dim3(256), 0, stream>>>(qkv, sa_qs + l * 64, Kn, Vt, Opar, Lpar, 1600, 25);
    attn_fin<<<dim3(N_TOK), dim3(256), 0, stream>>>(Opar, Lpar, ob, 63.0f);
    gemm_bt<2, 4><<<dim3(12, 8, 4), dim3(256), 0, stream>>>(ob, swo, h, 1024, N_TOK, 1024, 1024, 1024, 1024);

    // ---- cross-attention ----
    ln_bf16<<<dim3(N_TOK), dim3(256), 0, stream>>>(h, DMODEL, ca_g + l * DMODEL, xnb, DMODEL, DMODEL, DMODEL);
    hipMemsetAsync(qkv, 0, (size_t)N_TOK * 3072 * 4, stream);
    gemm_bt<2, 4><<<dim3(12, 8, 4), dim3(256), 0, stream>>>(xnb, cwq, qkv, 3072, N_TOK, 1024, 1024, 1024, 1024);
    gemm_bt<2, 4><<<dim3(4, 16, 4), dim3(256), 0, stream>>>(ctxb, cwkv, qkv + 1024, 3072, NCTX, 2048, 1024, 1024, 1024);
    prep_kv<<<dim3(9, NHEAD), dim3(256), 0, stream>>>(qkv + 1024, ca_null + l * 2048, ca_ks + l * 64, Kn, Vt, 513, 576);
    attn_mfma<<<dim3(768), dim3(256), 0, stream>>>(qkv, ca_qs + l * 64, Kn, Vt, Opar, Lpar, 576, 9);
    attn_fin<<<dim3(N_TOK), dim3(256), 0, stream>>>(Opar, Lpar, ob, 63.0f);
    gemm_bt<2, 4><<<dim3(12, 8, 4), dim3(256), 0, stream>>>(ob, cwo, h, 1024, N_TOK, 1024, 1024, 1024, 1024);

    // ---- GEGLU feedforward ----
    ln_bf16<<<dim3(N_TOK), dim3(256), 0, stream>>>(h, DMODEL, ff_g1 + l * DMODEL, xnb, DMODEL, DMODEL, DMODEL);
    gemm_bt<0, 1><<<dim3(12, 43, 1), dim3(256), 0, stream>>>(xnb, fw1, h1, FF1P, N_TOK, FF1P, 1024, 1024, 1024);
    geglu_ln<<<dim3(N_TOK), dim3(256), 0, stream>>>(h1, ff_g2 + l * INNERD, xnb);
    gemm_bt<2, 4><<<dim3(12, 8, 4), dim3(256), 0, stream>>>(xnb, fw2, h, 1024, N_TOK, 1024, INNERP, INNERP, INNERP);
  }

  // ---- final LN + logits ----
  ln_bf16<<<dim3(N_TOK), dim3(256), 0, stream>>>(h, DMODEL, final_g, xnb, DMODEL, DMODEL, DMODEL);
  gemm_bt<0, 1><<<dim3(12, 64, 1), dim3(256), 0, stream>>>(xnb, logits_t, (float*)d_out, VOCAB, N_TOK, VOCAB, 1024, 1024, 1024);
}